// Round 10
// baseline (259.614 us; speedup 1.0000x reference)
//
#include <hip/hip_runtime.h>
#include <hip/hip_bf16.h>

// B=2, L=256, D=128, H=256 fast-weight (TTT-style) forward.
// Exact rewrite: sequential momentum/weight-decay scan -> decay-weighted
// attention with composed decay matrix S = wd_cs @ mom_cs via the stable
// O(L^2) recurrence (all exponents <= 0 in the live region).
//
// v10: every stage is a tiled GEMM (TM=16 tokens x TN=128 outputs, 256 thr,
// thread=2x4 acc, LDS-staged A-tile, wb[16] B-prefetch): each streamed
// float4 feeds 16 dot products (8x the reuse of v9). 8 launches:
// k_pre -> kA(qkv + gate scan) -> kBE(Z1/z1q || score1) -> kC(Z2->gZ2)
// -> kD(gX2->gZ1) -> kF(Zq1) -> kG(score2) -> kH(Zq2).

#define Bc 2
#define Lc 256
#define Dc 128
#define Hc 256

__device__ __forceinline__ float sigf(float z)  { return 1.f / (1.f + expf(-z)); }
__device__ __forceinline__ float siluf(float z) { return z * sigf(z); }
// replicates reference silu_backward exactly: s + sigmoid(z)*(1-s), s=silu(z)
__device__ __forceinline__ float silubwdf(float z) {
    float sg = sigf(z);
    float s  = z * sg;
    return s + sg * (1.f - s);
}
__device__ __forceinline__ float softplusf(float z) {
    if (z > 20.f)  return z;
    if (z < -20.f) return expf(z);
    return log1pf(expf(z));
}
__device__ __forceinline__ float dot4(float4 a, float4 b) {
    return a.x*b.x + a.y*b.y + a.z*b.z + a.w*b.w;
}

// ---- GEMM microkernel pieces: C-tile 16(m) x 128(n), 256 threads ----------
// thread: ty=tid>>5 (8), tx=tid&31 (32); owns rows m0+2ty+{0,1}, cols n0+4tx+{0..3}

__device__ __forceinline__ void mk_load_A(float* As, const float* Ag,
                                          int m0, int K, int tid) {
    const int n4 = 16 * K / 4;
    const float4* Ag4 = (const float4*)(Ag + (size_t)m0 * K);
    float4* As4 = (float4*)As;
    for (int idx = tid; idx < n4; idx += 256) As4[idx] = Ag4[idx];
}

// Bg pre-offset by n0 floats; ldb4 = ldb/4. Keff multiple of 16.
__device__ __forceinline__ void mk_gemm(const float* As, int K, int Keff,
                                        const float* Bg, int ldb4, int tid,
                                        float acc[2][4]) {
    const int ty = tid >> 5, tx = tid & 31;
    const float* a0p = As + (2 * ty) * K;
    const float* a1p = a0p + K;
    const float4* B4 = (const float4*)Bg + tx;
    for (int k0 = 0; k0 < Keff; k0 += 16) {
        float4 wb[16];
        #pragma unroll
        for (int u = 0; u < 16; ++u) wb[u] = B4[(size_t)(k0 + u) * ldb4];
        #pragma unroll
        for (int u = 0; u < 16; ++u) {
            float a0 = a0p[k0 + u], a1 = a1p[k0 + u];
            acc[0][0] += a0 * wb[u].x; acc[0][1] += a0 * wb[u].y;
            acc[0][2] += a0 * wb[u].z; acc[0][3] += a0 * wb[u].w;
            acc[1][0] += a1 * wb[u].x; acc[1][1] += a1 * wb[u].y;
            acc[1][2] += a1 * wb[u].z; acc[1][3] += a1 * wb[u].w;
        }
    }
}

// ---------------------------------------------------------------------------
// k_pre: 5 transposes via 32x33 LDS tiles. 112 blocks x 256 threads.
//   WqT/WkT/WvT: [d][n] from W[n][d]; W1T: [d][h]; W2T: [h][d].
// ---------------------------------------------------------------------------
__global__ __launch_bounds__(256) void k_pre(
    const float* __restrict__ Wq, const float* __restrict__ Wk,
    const float* __restrict__ Wv, const float* __restrict__ W1,
    const float* __restrict__ W2,
    float* __restrict__ WqT, float* __restrict__ WkT, float* __restrict__ WvT,
    float* __restrict__ W1T, float* __restrict__ W2T)
{
    __shared__ float tile[32][33];
    const int bb = blockIdx.x;
    const float* src; float* dst; int R, C, t0;
    if      (bb < 16) { src = Wq; dst = WqT; R = 128; C = 128; t0 = bb;      }
    else if (bb < 32) { src = Wk; dst = WkT; R = 128; C = 128; t0 = bb - 16; }
    else if (bb < 48) { src = Wv; dst = WvT; R = 128; C = 128; t0 = bb - 32; }
    else if (bb < 80) { src = W1; dst = W1T; R = 256; C = 128; t0 = bb - 48; }
    else              { src = W2; dst = W2T; R = 128; C = 256; t0 = bb - 80; }
    const int tilesC = C >> 5;
    const int tr = t0 / tilesC, tc = t0 % tilesC;
    const int i = threadIdx.x >> 5, j = threadIdx.x & 31;
    #pragma unroll
    for (int p = 0; p < 4; ++p)
        tile[i + p*8][j] = src[(tr*32 + i + p*8) * C + tc*32 + j];
    __syncthreads();
    #pragma unroll
    for (int p = 0; p < 4; ++p)
        dst[(tc*32 + i + p*8) * R + tr*32 + j] = tile[j][i + p*8];
}

// ---------------------------------------------------------------------------
// kA: blocks 0..95: q/k/v GEMM (M=512 x-rows, 3 n-tiles of 128, K=128).
//     blocks 96/97: gate/decay scan (one per batch).
// ---------------------------------------------------------------------------
__global__ __launch_bounds__(256, 2) void kA(
    const float* __restrict__ x,
    const float* __restrict__ WqT, const float* __restrict__ WkT,
    const float* __restrict__ WvT,
    const float* __restrict__ bq, const float* __restrict__ bk,
    const float* __restrict__ bv,
    const float* __restrict__ Wlr, const float* __restrict__ blr,
    const float* __restrict__ Wm,  const float* __restrict__ bm,
    const float* __restrict__ Wwd, const float* __restrict__ bwd,
    float* __restrict__ qo, float* __restrict__ ko, float* __restrict__ vo,
    float* __restrict__ KTr, float* __restrict__ Ssc, float* __restrict__ wdf)
{
    __shared__ __align__(16) float As[16 * 128];
    __shared__ float lrS[Lc], lwS[Lc], ewdS[Lc], clmS[Lc], cwdS[Lc];
    const int bb  = blockIdx.x;
    const int tid = threadIdx.x;

    if (bb < 96) {
        const int nt = bb % 3, m0 = (bb / 3) * 16;
        mk_load_A(As, x, m0, 128, tid);
        __syncthreads();
        float acc[2][4] = {};
        const float* Bsel = nt == 0 ? WqT : nt == 1 ? WkT : WvT;
        mk_gemm(As, 128, 128, Bsel, 32, tid, acc);
        const int ty = tid >> 5, tx = tid & 31;
        const float* bias = nt == 0 ? bq : nt == 1 ? bk : bv;
        float4 bv4 = *(const float4*)(bias + 4 * tx);
        #pragma unroll
        for (int r = 0; r < 2; ++r) {
            const int t = m0 + 2 * ty + r;
            float4 o = make_float4(acc[r][0] + bv4.x, acc[r][1] + bv4.y,
                                   acc[r][2] + bv4.z, acc[r][3] + bv4.w);
            if (nt == 0) {
                ((float4*)(qo + t * 128))[tx] = o;
            } else if (nt == 1) {
                ((float4*)(ko + t * 128))[tx] = o;
                const int b = t >> 8, l = t & 255;
                float vals[4] = {o.x, o.y, o.z, o.w};
                #pragma unroll
                for (int j = 0; j < 4; ++j)
                    KTr[b * 32768 + (4 * tx + j) * 256 + l] = vals[j];
            } else {
                ((float4*)(vo + t * 128))[tx] = o;
            }
        }
        return;
    }

    // ---- gate/decay scan ----
    const int b = bb - 96;
    const int l = tid;
    {
        const float4* xr4 = (const float4*)(x + (b * Lc + l) * Dc);
        const float4* wl4 = (const float4*)Wlr;
        const float4* wm4 = (const float4*)Wm;
        const float4* ww4 = (const float4*)Wwd;
        float dlr = blr[0], dm = bm[0], dw = bwd[0];
        #pragma unroll 4
        for (int j = 0; j < Dc / 4; ++j) {
            float4 xv = xr4[j];
            dlr += dot4(wl4[j], xv);
            dm  += dot4(wm4[j], xv);
            dw  += dot4(ww4[j], xv);
        }
        lrS[l] = softplusf(dlr);
        float lm = -softplusf(-dm);   // log sigmoid
        float lw = -softplusf(-dw);
        lwS[l]  = lw;
        clmS[l] = lm;
        cwdS[l] = lw;
    }
    __syncthreads();
    for (int off = 1; off < Lc; off <<= 1) {
        float a = (l >= off) ? clmS[l - off] : 0.f;
        float c = (l >= off) ? cwdS[l - off] : 0.f;
        __syncthreads();
        clmS[l] += a; cwdS[l] += c;
        __syncthreads();
    }
    wdf[b * Lc + l] = expf(cwdS[l]);
    ewdS[l] = __expf(lwS[l]);
    __syncthreads();
    {
        const int   m     = l;
        const float clm_m = clmS[m];
        const float lrm   = lrS[m];
        float* outp = Ssc + (b * Lc) * Lc + m;
        float s = 0.f;
        for (int ll = 0; ll < Lc; ++ll) {
            float e2 = __expf(clmS[ll] - clm_m);
            s = (ll >= m) ? (ewdS[ll] * s + e2) : 0.f;
            outp[ll * Lc] = s * lrm;     // row-major Ssc[t][m], coalesced in m
        }
    }
}

// ---------------------------------------------------------------------------
// kBE: blocks 0..127: Z1/z1q GEMM (M=1024 = ko||qo rows, N=256, K=128).
//      blocks 128..191: score1 (M=512 qo rows, N=256 m, K=128, causal).
// ---------------------------------------------------------------------------
__global__ __launch_bounds__(256, 2) void kBE(
    const float* __restrict__ ko_qo,   // ko at +0, qo at +65536 (M=1024)
    const float* __restrict__ qo,
    const float* __restrict__ W1T, const float* __restrict__ b1v,
    const float* __restrict__ KTr, const float* __restrict__ Ssc,
    float* __restrict__ Z1row, float* __restrict__ X2row,
    float* __restrict__ X2Tr, float* __restrict__ z1qrow,
    float* __restrict__ arow1)
{
    __shared__ __align__(16) float As[16 * 128];
    const int bb  = blockIdx.x;
    const int tid = threadIdx.x;
    const int ty = tid >> 5, tx = tid & 31;

    if (bb < 128) {
        const int nt = bb & 1, m0g = (bb >> 1) * 16;
        const int n0 = nt * 128;
        mk_load_A(As, ko_qo, m0g, 128, tid);
        __syncthreads();
        float acc[2][4] = {};
        mk_gemm(As, 128, 128, W1T + n0, 64, tid, acc);
        float4 b14 = *(const float4*)(b1v + n0 + 4 * tx);
        #pragma unroll
        for (int r = 0; r < 2; ++r) {
            float4 z = make_float4(acc[r][0] + b14.x, acc[r][1] + b14.y,
                                   acc[r][2] + b14.z, acc[r][3] + b14.w);
            if (m0g < 512) {
                const int t = m0g + 2 * ty + r;
                ((float4*)(Z1row + t * 256 + n0))[tx] = z;
                float4 s = make_float4(siluf(z.x), siluf(z.y),
                                       siluf(z.z), siluf(z.w));
                ((float4*)(X2row + t * 256 + n0))[tx] = s;
                const int b = t >> 8, l = t & 255;
                float vals[4] = {s.x, s.y, s.z, s.w};
                #pragma unroll
                for (int j = 0; j < 4; ++j)
                    X2Tr[b * 65536 + (n0 + 4 * tx + j) * 256 + l] = vals[j];
            } else {
                const int t = m0g - 512 + 2 * ty + r;
                ((float4*)(z1qrow + t * 256 + n0))[tx] = z;
            }
        }
        return;
    }

    // ---- score1: arow1[t][m] = Ssc[t][m]*(q[t].k[m] + 1) ----
    const int eb = bb - 128;
    const int nt = eb & 1, m0 = (eb >> 1) * 16;
    const int n0 = nt * 128;
    const int l0 = m0 & 255;
    if (n0 > l0 + 15) return;            // causal tile skip (Ssc==0 there)
    mk_load_A(As, qo, m0, 128, tid);
    __syncthreads();
    float acc[2][4] = {};
    mk_gemm(As, 128, 128, KTr + (m0 >> 8) * 32768 + n0, 64, tid, acc);
    #pragma unroll
    for (int r = 0; r < 2; ++r) {
        const int t = m0 + 2 * ty + r;
        float4 s4 = ((const float4*)(Ssc + t * 256 + n0))[tx];
        float4 o = make_float4(s4.x * (acc[r][0] + 1.f),
                               s4.y * (acc[r][1] + 1.f),
                               s4.z * (acc[r][2] + 1.f),
                               s4.w * (acc[r][3] + 1.f));
        ((float4*)(arow1 + t * 256 + n0))[tx] = o;
    }
}

// ---------------------------------------------------------------------------
// kC: Z2 -> gZ2. M=512 (X2row), N=128, K=256. 32 blocks.
// ---------------------------------------------------------------------------
__global__ __launch_bounds__(256, 2) void kC(
    const float* __restrict__ X2row, const float* __restrict__ W2T,
    const float* __restrict__ b2v, const float* __restrict__ vo,
    float* __restrict__ gZ2row)
{
    __shared__ __align__(16) float As[16 * 256];
    const int tid = threadIdx.x;
    const int ty = tid >> 5, tx = tid & 31;
    const int m0 = blockIdx.x * 16;
    mk_load_A(As, X2row, m0, 256, tid);
    __syncthreads();
    float acc[2][4] = {};
    mk_gemm(As, 256, 256, W2T, 32, tid, acc);
    float4 b24 = *(const float4*)(b2v + 4 * tx);
    #pragma unroll
    for (int r = 0; r < 2; ++r) {
        const int t = m0 + 2 * ty + r;
        float4 v4 = ((const float4*)(vo + t * 128))[tx];
        ((float4*)(gZ2row + t * 128))[tx] =
            make_float4(acc[r][0] + b24.x - v4.x, acc[r][1] + b24.y - v4.y,
                        acc[r][2] + b24.z - v4.z, acc[r][3] + b24.w - v4.w);
    }
}

// ---------------------------------------------------------------------------
// kD: gX2 -> gZ1. M=512 (gZ2row), N=256, K=128, B=W2 (input, row-major).
// ---------------------------------------------------------------------------
__global__ __launch_bounds__(256, 2) void kD(
    const float* __restrict__ gZ2row, const float* __restrict__ W2,
    const float* __restrict__ Z1row, float* __restrict__ gZ1row)
{
    __shared__ __align__(16) float As[16 * 128];
    const int tid = threadIdx.x;
    const int ty = tid >> 5, tx = tid & 31;
    const int nt = blockIdx.x & 1, m0 = (blockIdx.x >> 1) * 16;
    const int n0 = nt * 128;
    mk_load_A(As, gZ2row, m0, 128, tid);
    __syncthreads();
    float acc[2][4] = {};
    mk_gemm(As, 128, 128, W2 + n0, 64, tid, acc);
    #pragma unroll
    for (int r = 0; r < 2; ++r) {
        const int t = m0 + 2 * ty + r;
        float4 z1 = ((const float4*)(Z1row + t * 256 + n0))[tx];
        ((float4*)(gZ1row + t * 256 + n0))[tx] =
            make_float4(acc[r][0] * silubwdf(z1.x), acc[r][1] * silubwdf(z1.y),
                        acc[r][2] * silubwdf(z1.z), acc[r][3] * silubwdf(z1.w));
    }
}

// ---------------------------------------------------------------------------
// kF: Zq1 + silu. M=512 (arow1), N=256 h, K=causal(l0+16), B=gZ1row[b].
// ---------------------------------------------------------------------------
__global__ __launch_bounds__(256, 2) void kF(
    const float* __restrict__ arow1, const float* __restrict__ gZ1row,
    const float* __restrict__ z1qrow, const float* __restrict__ wdf,
    float* __restrict__ Xq2row)
{
    __shared__ __align__(16) float As[16 * 256];
    const int tid = threadIdx.x;
    const int ty = tid >> 5, tx = tid & 31;
    const int nt = blockIdx.x & 1, m0 = (blockIdx.x >> 1) * 16;
    const int n0 = nt * 128;
    const int Keff = (m0 & 255) + 16;
    mk_load_A(As, arow1, m0, 256, tid);
    __syncthreads();
    float acc[2][4] = {};
    mk_gemm(As, 256, Keff, gZ1row + (m0 >> 8) * 65536 + n0, 64, tid, acc);
    #pragma unroll
    for (int r = 0; r < 2; ++r) {
        const int t = m0 + 2 * ty + r;
        const float w = wdf[t];
        float4 zq = ((const float4*)(z1qrow + t * 256 + n0))[tx];
        ((float4*)(Xq2row + t * 256 + n0))[tx] =
            make_float4(siluf(acc[r][0] + w * zq.x), siluf(acc[r][1] + w * zq.y),
                        siluf(acc[r][2] + w * zq.z), siluf(acc[r][3] + w * zq.w));
    }
}

// ---------------------------------------------------------------------------
// kG: score2. M=512 (Xq2row), N=256 m, K=256 h, B=X2Tr[b]; causal skip.
// ---------------------------------------------------------------------------
__global__ __launch_bounds__(256, 2) void kG(
    const float* __restrict__ Xq2row, const float* __restrict__ X2Tr,
    const float* __restrict__ Ssc, float* __restrict__ arow2)
{
    __shared__ __align__(16) float As[16 * 256];
    const int tid = threadIdx.x;
    const int ty = tid >> 5, tx = tid & 31;
    const int nt = blockIdx.x & 1, m0 = (blockIdx.x >> 1) * 16;
    const int n0 = nt * 128;
    const int l0 = m0 & 255;
    if (n0 > l0 + 15) return;            // causal tile skip
    mk_load_A(As, Xq2row, m0, 256, tid);
    __syncthreads();
    float acc[2][4] = {};
    mk_gemm(As, 256, 256, X2Tr + (m0 >> 8) * 65536 + n0, 64, tid, acc);
    #pragma unroll
    for (int r = 0; r < 2; ++r) {
        const int t = m0 + 2 * ty + r;
        float4 s4 = ((const float4*)(Ssc + t * 256 + n0))[tx];
        ((float4*)(arow2 + t * 256 + n0))[tx] =
            make_float4(s4.x * (acc[r][0] + 1.f), s4.y * (acc[r][1] + 1.f),
                        s4.z * (acc[r][2] + 1.f), s4.w * (acc[r][3] + 1.f));
    }
}

// ---------------------------------------------------------------------------
// kH: Zq2. out = arow2 @ gZ2row[b] (K=causal) + wdf*(b2 + Xq2row @ W2T).
// M=512, N=128. 32 blocks.
// ---------------------------------------------------------------------------
__global__ __launch_bounds__(256, 2) void kH(
    const float* __restrict__ arow2, const float* __restrict__ gZ2row,
    const float* __restrict__ Xq2row, const float* __restrict__ W2T,
    const float* __restrict__ b2v, const float* __restrict__ wdf,
    float* __restrict__ out)
{
    __shared__ __align__(16) float As1[16 * 256];
    __shared__ __align__(16) float As2[16 * 256];
    const int tid = threadIdx.x;
    const int ty = tid >> 5, tx = tid & 31;
    const int m0 = blockIdx.x * 16;
    const int Keff = (m0 & 255) + 16;
    mk_load_A(As1, arow2, m0, 256, tid);
    mk_load_A(As2, Xq2row, m0, 256, tid);
    __syncthreads();
    float acc1[2][4] = {}, acc2[2][4] = {};
    mk_gemm(As1, 256, Keff, gZ2row + (m0 >> 8) * 32768, 32, tid, acc1);
    mk_gemm(As2, 256, 256, W2T, 32, tid, acc2);
    float4 b24 = *(const float4*)(b2v + 4 * tx);
    #pragma unroll
    for (int r = 0; r < 2; ++r) {
        const int t = m0 + 2 * ty + r;
        const float w = wdf[t];
        ((float4*)(out + t * 128))[tx] =
            make_float4(acc1[r][0] + w * (b24.x + acc2[r][0]),
                        acc1[r][1] + w * (b24.y + acc2[r][1]),
                        acc1[r][2] + w * (b24.z + acc2[r][2]),
                        acc1[r][3] + w * (b24.w + acc2[r][3]));
    }
}

// ---------------------------------------------------------------------------
extern "C" void kernel_launch(void* const* d_in, const int* in_sizes, int n_in,
                              void* d_out, int out_size, void* d_ws, size_t ws_size,
                              hipStream_t stream)
{
    const float* x   = (const float*)d_in[0];
    const float* W1  = (const float*)d_in[1];
    const float* b1  = (const float*)d_in[2];
    const float* W2  = (const float*)d_in[3];
    const float* b2  = (const float*)d_in[4];
    const float* Wq  = (const float*)d_in[5];
    const float* bq  = (const float*)d_in[6];
    const float* Wk  = (const float*)d_in[7];
    const float* bk  = (const float*)d_in[8];
    const float* Wv  = (const float*)d_in[9];
    const float* bv  = (const float*)d_in[10];
    const float* Wlr = (const float*)d_in[11];
    const float* blr = (const float*)d_in[12];
    const float* Wm  = (const float*)d_in[13];
    const float* bm  = (const float*)d_in[14];
    const float* Wwd = (const float*)d_in[15];
    const float* bwd = (const float*)d_in[16];

    float* ws = (float*)d_ws;
    float* ko     = ws + 0;         // 512x128  (must precede qo: kBE M=1024)
    float* qo     = ws + 65536;     // 512x128
    float* vo     = ws + 131072;    // 512x128
    float* Z1row  = ws + 196608;    // 512x256
    float* X2row  = ws + 327680;    // 512x256
    float* z1qrow = ws + 458752;    // 512x256
    float* gZ2row = ws + 589824;    // 512x128
    float* gZ1row = ws + 655360;    // 512x256
    float* Xq2row = ws + 786432;    // 512x256
    float* arow1  = ws + 917504;    // 512x256
    float* arow2  = ws + 1048576;   // 512x256
    float* KTr    = ws + 1179648;   // 2 x 128 x 256
    float* X2Tr   = ws + 1245184;   // 2 x 256 x 256
    float* Ssc    = ws + 1376256;   // 512x256
    float* wdf    = ws + 1507328;   // 512
    float* WqT    = ws + 1507840;   // 128x128
    float* WkT    = ws + 1524224;
    float* WvT    = ws + 1540608;
    float* W1T    = ws + 1556992;   // 128x256
    float* W2T    = ws + 1589760;   // 256x128
    float* out    = (float*)d_out;

    k_pre<<<112, 256, 0, stream>>>(Wq, Wk, Wv, W1, W2, WqT, WkT, WvT, W1T, W2T);
    kA<<<98, 256, 0, stream>>>(x, WqT, WkT, WvT, bq, bk, bv,
                               Wlr, blr, Wm, bm, Wwd, bwd,
                               qo, ko, vo, KTr, Ssc, wdf);
    kBE<<<192, 256, 0, stream>>>(ko, qo, W1T, b1, KTr, Ssc,
                                 Z1row, X2row, X2Tr, z1qrow, arow1);
    kC<<<32, 256, 0, stream>>>(X2row, W2T, b2, vo, gZ2row);
    kD<<<64, 256, 0, stream>>>(gZ2row, W2, Z1row, gZ1row);
    kF<<<64, 256, 0, stream>>>(arow1, gZ1row, z1qrow, wdf, Xq2row);
    kG<<<64, 256, 0, stream>>>(Xq2row, X2Tr, Ssc, arow2);
    kH<<<32, 256, 0, stream>>>(arow2, gZ2row, Xq2row, W2T, b2, wdf, out);
}

// Round 11
// 223.196 us; speedup vs baseline: 1.1632x; 1.1632x over previous
//
#include <hip/hip_runtime.h>
#include <hip/hip_bf16.h>

// B=2, L=256, D=128, H=256 fast-weight (TTT-style) forward.
// Exact rewrite: sequential momentum/weight-decay scan -> decay-weighted
// attention with composed decay matrix S = wd_cs @ mom_cs via the stable
// O(L^2) recurrence (all exponents <= 0 in the live region).
//
// v11 = v10 (tiled-GEMM stages, 16x reuse) with the HBM write-amplification
// bug fixed: transposed outputs (KTr, X2Tr) are staged in LDS per tile and
// written as contiguous float4 runs along l (64B-granular coalesced stores)
// instead of 4B scatter stores at 1KB stride (which caused 30x RMW traffic,
// kBE FETCH 28MB/WRITE 56MB -> dur 50us in R10).

#define Bc 2
#define Lc 256
#define Dc 128
#define Hc 256

__device__ __forceinline__ float sigf(float z)  { return 1.f / (1.f + expf(-z)); }
__device__ __forceinline__ float siluf(float z) { return z * sigf(z); }
// replicates reference silu_backward exactly: s + sigmoid(z)*(1-s), s=silu(z)
__device__ __forceinline__ float silubwdf(float z) {
    float sg = sigf(z);
    float s  = z * sg;
    return s + sg * (1.f - s);
}
__device__ __forceinline__ float softplusf(float z) {
    if (z > 20.f)  return z;
    if (z < -20.f) return expf(z);
    return log1pf(expf(z));
}
__device__ __forceinline__ float dot4(float4 a, float4 b) {
    return a.x*b.x + a.y*b.y + a.z*b.z + a.w*b.w;
}

// ---- GEMM microkernel: C-tile 16(m) x 128(n), 256 threads -----------------
// thread: ty=tid>>5 (8), tx=tid&31 (32); owns rows m0+2ty+{0,1}, cols 4tx+{0..3}

__device__ __forceinline__ void mk_load_A(float* As, const float* Ag,
                                          int m0, int K, int tid) {
    const int n4 = 16 * K / 4;
    const float4* Ag4 = (const float4*)(Ag + (size_t)m0 * K);
    float4* As4 = (float4*)As;
    for (int idx = tid; idx < n4; idx += 256) As4[idx] = Ag4[idx];
}

// Bg pre-offset by n0 floats; ldb4 = ldb/4. Keff multiple of 16.
__device__ __forceinline__ void mk_gemm(const float* As, int K, int Keff,
                                        const float* Bg, int ldb4, int tid,
                                        float acc[2][4]) {
    const int ty = tid >> 5, tx = tid & 31;
    const float* a0p = As + (2 * ty) * K;
    const float* a1p = a0p + K;
    const float4* B4 = (const float4*)Bg + tx;
    for (int k0 = 0; k0 < Keff; k0 += 16) {
        float4 wb[16];
        #pragma unroll
        for (int u = 0; u < 16; ++u) wb[u] = B4[(size_t)(k0 + u) * ldb4];
        #pragma unroll
        for (int u = 0; u < 16; ++u) {
            float a0 = a0p[k0 + u], a1 = a1p[k0 + u];
            acc[0][0] += a0 * wb[u].x; acc[0][1] += a0 * wb[u].y;
            acc[0][2] += a0 * wb[u].z; acc[0][3] += a0 * wb[u].w;
            acc[1][0] += a1 * wb[u].x; acc[1][1] += a1 * wb[u].y;
            acc[1][2] += a1 * wb[u].z; acc[1][3] += a1 * wb[u].w;
        }
    }
}

// ---------------------------------------------------------------------------
// k_pre: 5 transposes via 32x33 LDS tiles. 112 blocks x 256 threads.
// ---------------------------------------------------------------------------
__global__ __launch_bounds__(256) void k_pre(
    const float* __restrict__ Wq, const float* __restrict__ Wk,
    const float* __restrict__ Wv, const float* __restrict__ W1,
    const float* __restrict__ W2,
    float* __restrict__ WqT, float* __restrict__ WkT, float* __restrict__ WvT,
    float* __restrict__ W1T, float* __restrict__ W2T)
{
    __shared__ float tile[32][33];
    const int bb = blockIdx.x;
    const float* src; float* dst; int R, C, t0;
    if      (bb < 16) { src = Wq; dst = WqT; R = 128; C = 128; t0 = bb;      }
    else if (bb < 32) { src = Wk; dst = WkT; R = 128; C = 128; t0 = bb - 16; }
    else if (bb < 48) { src = Wv; dst = WvT; R = 128; C = 128; t0 = bb - 32; }
    else if (bb < 80) { src = W1; dst = W1T; R = 256; C = 128; t0 = bb - 48; }
    else              { src = W2; dst = W2T; R = 128; C = 256; t0 = bb - 80; }
    const int tilesC = C >> 5;
    const int tr = t0 / tilesC, tc = t0 % tilesC;
    const int i = threadIdx.x >> 5, j = threadIdx.x & 31;
    #pragma unroll
    for (int p = 0; p < 4; ++p)
        tile[i + p*8][j] = src[(tr*32 + i + p*8) * C + tc*32 + j];
    __syncthreads();
    #pragma unroll
    for (int p = 0; p < 4; ++p)
        dst[(tc*32 + i + p*8) * R + tr*32 + j] = tile[j][i + p*8];
}

// ---------------------------------------------------------------------------
// kA: blocks 0..95: q/k/v GEMM (M=512, 3 n-tiles, K=128).
//     blocks 96/97: gate/decay scan (one per batch).
// ---------------------------------------------------------------------------
__global__ __launch_bounds__(256, 2) void kA(
    const float* __restrict__ x,
    const float* __restrict__ WqT, const float* __restrict__ WkT,
    const float* __restrict__ WvT,
    const float* __restrict__ bq, const float* __restrict__ bk,
    const float* __restrict__ bv,
    const float* __restrict__ Wlr, const float* __restrict__ blr,
    const float* __restrict__ Wm,  const float* __restrict__ bm,
    const float* __restrict__ Wwd, const float* __restrict__ bwd,
    float* __restrict__ qo, float* __restrict__ ko, float* __restrict__ vo,
    float* __restrict__ KTr, float* __restrict__ Ssc, float* __restrict__ wdf)
{
    __shared__ __align__(16) float As[16 * 128];
    __shared__ __align__(16) float kt[16][128];
    __shared__ float lrS[Lc], lwS[Lc], ewdS[Lc], clmS[Lc], cwdS[Lc];
    const int bb  = blockIdx.x;
    const int tid = threadIdx.x;

    if (bb < 96) {
        const int nt = bb % 3, m0 = (bb / 3) * 16;
        mk_load_A(As, x, m0, 128, tid);
        __syncthreads();
        float acc[2][4] = {};
        const float* Bsel = nt == 0 ? WqT : nt == 1 ? WkT : WvT;
        mk_gemm(As, 128, 128, Bsel, 32, tid, acc);
        const int ty = tid >> 5, tx = tid & 31;
        const float* bias = nt == 0 ? bq : nt == 1 ? bk : bv;
        float4 bv4 = *(const float4*)(bias + 4 * tx);
        #pragma unroll
        for (int r = 0; r < 2; ++r) {
            const int t = m0 + 2 * ty + r;
            float4 o = make_float4(acc[r][0] + bv4.x, acc[r][1] + bv4.y,
                                   acc[r][2] + bv4.z, acc[r][3] + bv4.w);
            if (nt == 0) {
                ((float4*)(qo + t * 128))[tx] = o;
            } else if (nt == 1) {
                ((float4*)(ko + t * 128))[tx] = o;
                kt[2 * ty + r][4 * tx + 0] = o.x;
                kt[2 * ty + r][4 * tx + 1] = o.y;
                kt[2 * ty + r][4 * tx + 2] = o.z;
                kt[2 * ty + r][4 * tx + 3] = o.w;
            } else {
                ((float4*)(vo + t * 128))[tx] = o;
            }
        }
        if (nt == 1) {
            __syncthreads();
            // coalesced transpose write: KTr[b][d][l0..l0+15], float4 runs in l
            const int b = m0 >> 8, l0 = m0 & 255;
            for (int idx = tid; idx < 512; idx += 256) {
                const int d = idx >> 2, l4 = idx & 3;
                float4 v = make_float4(kt[4*l4+0][d], kt[4*l4+1][d],
                                       kt[4*l4+2][d], kt[4*l4+3][d]);
                *(float4*)(KTr + b * 32768 + d * 256 + l0 + 4 * l4) = v;
            }
        }
        return;
    }

    // ---- gate/decay scan ----
    const int b = bb - 96;
    const int l = tid;
    {
        const float4* xr4 = (const float4*)(x + (b * Lc + l) * Dc);
        const float4* wl4 = (const float4*)Wlr;
        const float4* wm4 = (const float4*)Wm;
        const float4* ww4 = (const float4*)Wwd;
        float dlr = blr[0], dm = bm[0], dw = bwd[0];
        #pragma unroll 4
        for (int j = 0; j < Dc / 4; ++j) {
            float4 xv = xr4[j];
            dlr += dot4(wl4[j], xv);
            dm  += dot4(wm4[j], xv);
            dw  += dot4(ww4[j], xv);
        }
        lrS[l] = softplusf(dlr);
        float lm = -softplusf(-dm);   // log sigmoid
        float lw = -softplusf(-dw);
        lwS[l]  = lw;
        clmS[l] = lm;
        cwdS[l] = lw;
    }
    __syncthreads();
    for (int off = 1; off < Lc; off <<= 1) {
        float a = (l >= off) ? clmS[l - off] : 0.f;
        float c = (l >= off) ? cwdS[l - off] : 0.f;
        __syncthreads();
        clmS[l] += a; cwdS[l] += c;
        __syncthreads();
    }
    wdf[b * Lc + l] = expf(cwdS[l]);
    ewdS[l] = __expf(lwS[l]);
    __syncthreads();
    {
        const int   m     = l;
        const float clm_m = clmS[m];
        const float lrm   = lrS[m];
        float* outp = Ssc + (b * Lc) * Lc + m;
        float s = 0.f;
        for (int ll = 0; ll < Lc; ++ll) {
            float e2 = __expf(clmS[ll] - clm_m);
            s = (ll >= m) ? (ewdS[ll] * s + e2) : 0.f;
            outp[ll * Lc] = s * lrm;     // row-major Ssc[t][m], coalesced in m
        }
    }
}

// ---------------------------------------------------------------------------
// kBE: blocks 0..127: Z1/z1q GEMM (M=1024 = ko||qo rows, N=256, K=128).
//      blocks 128..191: score1 (causal tile skip).
// ---------------------------------------------------------------------------
__global__ __launch_bounds__(256, 2) void kBE(
    const float* __restrict__ ko_qo,   // ko at +0, qo at +65536 (M=1024)
    const float* __restrict__ qo,
    const float* __restrict__ W1T, const float* __restrict__ b1v,
    const float* __restrict__ KTr, const float* __restrict__ Ssc,
    float* __restrict__ Z1row, float* __restrict__ X2row,
    float* __restrict__ X2Tr, float* __restrict__ z1qrow,
    float* __restrict__ arow1)
{
    __shared__ __align__(16) float As[16 * 128];
    __shared__ __align__(16) float xt[16][128];
    const int bb  = blockIdx.x;
    const int tid = threadIdx.x;
    const int ty = tid >> 5, tx = tid & 31;

    if (bb < 128) {
        const int nt = bb & 1, m0g = (bb >> 1) * 16;
        const int n0 = nt * 128;
        mk_load_A(As, ko_qo, m0g, 128, tid);
        __syncthreads();
        float acc[2][4] = {};
        mk_gemm(As, 128, 128, W1T + n0, 64, tid, acc);
        float4 b14 = *(const float4*)(b1v + n0 + 4 * tx);
        if (m0g < 512) {
            #pragma unroll
            for (int r = 0; r < 2; ++r) {
                const int t = m0g + 2 * ty + r;
                float4 z = make_float4(acc[r][0] + b14.x, acc[r][1] + b14.y,
                                       acc[r][2] + b14.z, acc[r][3] + b14.w);
                ((float4*)(Z1row + t * 256 + n0))[tx] = z;
                float4 s = make_float4(siluf(z.x), siluf(z.y),
                                       siluf(z.z), siluf(z.w));
                ((float4*)(X2row + t * 256 + n0))[tx] = s;
                xt[2 * ty + r][4 * tx + 0] = s.x;
                xt[2 * ty + r][4 * tx + 1] = s.y;
                xt[2 * ty + r][4 * tx + 2] = s.z;
                xt[2 * ty + r][4 * tx + 3] = s.w;
            }
            __syncthreads();
            // coalesced transpose write: X2Tr[b][n0+h][l0..l0+15]
            const int b = m0g >> 8, l0 = m0g & 255;
            for (int idx = tid; idx < 512; idx += 256) {
                const int h = idx >> 2, l4 = idx & 3;
                float4 v = make_float4(xt[4*l4+0][h], xt[4*l4+1][h],
                                       xt[4*l4+2][h], xt[4*l4+3][h]);
                *(float4*)(X2Tr + b * 65536 + (n0 + h) * 256 + l0 + 4 * l4) = v;
            }
        } else {
            #pragma unroll
            for (int r = 0; r < 2; ++r) {
                const int t = m0g - 512 + 2 * ty + r;
                ((float4*)(z1qrow + t * 256 + n0))[tx] =
                    make_float4(acc[r][0] + b14.x, acc[r][1] + b14.y,
                                acc[r][2] + b14.z, acc[r][3] + b14.w);
            }
        }
        return;
    }

    // ---- score1: arow1[t][m] = Ssc[t][m]*(q[t].k[m] + 1) ----
    const int eb = bb - 128;
    const int nt = eb & 1, m0 = (eb >> 1) * 16;
    const int n0 = nt * 128;
    const int l0 = m0 & 255;
    if (n0 > l0 + 15) return;            // causal tile skip (Ssc==0 there)
    mk_load_A(As, qo, m0, 128, tid);
    __syncthreads();
    float acc[2][4] = {};
    mk_gemm(As, 128, 128, KTr + (m0 >> 8) * 32768 + n0, 64, tid, acc);
    #pragma unroll
    for (int r = 0; r < 2; ++r) {
        const int t = m0 + 2 * ty + r;
        float4 s4 = ((const float4*)(Ssc + t * 256 + n0))[tx];
        ((float4*)(arow1 + t * 256 + n0))[tx] =
            make_float4(s4.x * (acc[r][0] + 1.f), s4.y * (acc[r][1] + 1.f),
                        s4.z * (acc[r][2] + 1.f), s4.w * (acc[r][3] + 1.f));
    }
}

// ---------------------------------------------------------------------------
// kC: Z2 -> gZ2. M=512 (X2row), N=128, K=256. 32 blocks.
// ---------------------------------------------------------------------------
__global__ __launch_bounds__(256, 2) void kC(
    const float* __restrict__ X2row, const float* __restrict__ W2T,
    const float* __restrict__ b2v, const float* __restrict__ vo,
    float* __restrict__ gZ2row)
{
    __shared__ __align__(16) float As[16 * 256];
    const int tid = threadIdx.x;
    const int ty = tid >> 5, tx = tid & 31;
    const int m0 = blockIdx.x * 16;
    mk_load_A(As, X2row, m0, 256, tid);
    __syncthreads();
    float acc[2][4] = {};
    mk_gemm(As, 256, 256, W2T, 32, tid, acc);
    float4 b24 = *(const float4*)(b2v + 4 * tx);
    #pragma unroll
    for (int r = 0; r < 2; ++r) {
        const int t = m0 + 2 * ty + r;
        float4 v4 = ((const float4*)(vo + t * 128))[tx];
        ((float4*)(gZ2row + t * 128))[tx] =
            make_float4(acc[r][0] + b24.x - v4.x, acc[r][1] + b24.y - v4.y,
                        acc[r][2] + b24.z - v4.z, acc[r][3] + b24.w - v4.w);
    }
}

// ---------------------------------------------------------------------------
// kD: gX2 -> gZ1. M=512 (gZ2row), N=256, K=128, B=W2 (row-major input).
// ---------------------------------------------------------------------------
__global__ __launch_bounds__(256, 2) void kD(
    const float* __restrict__ gZ2row, const float* __restrict__ W2,
    const float* __restrict__ Z1row, float* __restrict__ gZ1row)
{
    __shared__ __align__(16) float As[16 * 128];
    const int tid = threadIdx.x;
    const int ty = tid >> 5, tx = tid & 31;
    const int nt = blockIdx.x & 1, m0 = (blockIdx.x >> 1) * 16;
    const int n0 = nt * 128;
    mk_load_A(As, gZ2row, m0, 128, tid);
    __syncthreads();
    float acc[2][4] = {};
    mk_gemm(As, 128, 128, W2 + n0, 64, tid, acc);
    #pragma unroll
    for (int r = 0; r < 2; ++r) {
        const int t = m0 + 2 * ty + r;
        float4 z1 = ((const float4*)(Z1row + t * 256 + n0))[tx];
        ((float4*)(gZ1row + t * 256 + n0))[tx] =
            make_float4(acc[r][0] * silubwdf(z1.x), acc[r][1] * silubwdf(z1.y),
                        acc[r][2] * silubwdf(z1.z), acc[r][3] * silubwdf(z1.w));
    }
}

// ---------------------------------------------------------------------------
// kF: Zq1 + silu. M=512 (arow1), N=256 h, K=causal(l0+16), B=gZ1row[b].
// ---------------------------------------------------------------------------
__global__ __launch_bounds__(256, 2) void kF(
    const float* __restrict__ arow1, const float* __restrict__ gZ1row,
    const float* __restrict__ z1qrow, const float* __restrict__ wdf,
    float* __restrict__ Xq2row)
{
    __shared__ __align__(16) float As[16 * 256];
    const int tid = threadIdx.x;
    const int ty = tid >> 5, tx = tid & 31;
    const int nt = blockIdx.x & 1, m0 = (blockIdx.x >> 1) * 16;
    const int n0 = nt * 128;
    const int Keff = (m0 & 255) + 16;
    mk_load_A(As, arow1, m0, 256, tid);
    __syncthreads();
    float acc[2][4] = {};
    mk_gemm(As, 256, Keff, gZ1row + (m0 >> 8) * 65536 + n0, 64, tid, acc);
    #pragma unroll
    for (int r = 0; r < 2; ++r) {
        const int t = m0 + 2 * ty + r;
        const float w = wdf[t];
        float4 zq = ((const float4*)(z1qrow + t * 256 + n0))[tx];
        ((float4*)(Xq2row + t * 256 + n0))[tx] =
            make_float4(siluf(acc[r][0] + w * zq.x), siluf(acc[r][1] + w * zq.y),
                        siluf(acc[r][2] + w * zq.z), siluf(acc[r][3] + w * zq.w));
    }
}

// ---------------------------------------------------------------------------
// kG: score2. M=512 (Xq2row), N=256 m, K=256 h, B=X2Tr[b]; causal skip.
// ---------------------------------------------------------------------------
__global__ __launch_bounds__(256, 2) void kG(
    const float* __restrict__ Xq2row, const float* __restrict__ X2Tr,
    const float* __restrict__ Ssc, float* __restrict__ arow2)
{
    __shared__ __align__(16) float As[16 * 256];
    const int tid = threadIdx.x;
    const int ty = tid >> 5, tx = tid & 31;
    const int nt = blockIdx.x & 1, m0 = (blockIdx.x >> 1) * 16;
    const int n0 = nt * 128;
    const int l0 = m0 & 255;
    if (n0 > l0 + 15) return;            // causal tile skip
    mk_load_A(As, Xq2row, m0, 256, tid);
    __syncthreads();
    float acc[2][4] = {};
    mk_gemm(As, 256, 256, X2Tr + (m0 >> 8) * 65536 + n0, 64, tid, acc);
    #pragma unroll
    for (int r = 0; r < 2; ++r) {
        const int t = m0 + 2 * ty + r;
        float4 s4 = ((const float4*)(Ssc + t * 256 + n0))[tx];
        ((float4*)(arow2 + t * 256 + n0))[tx] =
            make_float4(s4.x * (acc[r][0] + 1.f), s4.y * (acc[r][1] + 1.f),
                        s4.z * (acc[r][2] + 1.f), s4.w * (acc[r][3] + 1.f));
    }
}

// ---------------------------------------------------------------------------
// kH: Zq2. out = arow2 @ gZ2row[b] (K=causal) + wdf*(b2 + Xq2row @ W2T).
// ---------------------------------------------------------------------------
__global__ __launch_bounds__(256, 2) void kH(
    const float* __restrict__ arow2, const float* __restrict__ gZ2row,
    const float* __restrict__ Xq2row, const float* __restrict__ W2T,
    const float* __restrict__ b2v, const float* __restrict__ wdf,
    float* __restrict__ out)
{
    __shared__ __align__(16) float As1[16 * 256];
    __shared__ __align__(16) float As2[16 * 256];
    const int tid = threadIdx.x;
    const int ty = tid >> 5, tx = tid & 31;
    const int m0 = blockIdx.x * 16;
    const int Keff = (m0 & 255) + 16;
    mk_load_A(As1, arow2, m0, 256, tid);
    mk_load_A(As2, Xq2row, m0, 256, tid);
    __syncthreads();
    float acc1[2][4] = {}, acc2[2][4] = {};
    mk_gemm(As1, 256, Keff, gZ2row + (m0 >> 8) * 32768, 32, tid, acc1);
    mk_gemm(As2, 256, 256, W2T, 32, tid, acc2);
    float4 b24 = *(const float4*)(b2v + 4 * tx);
    #pragma unroll
    for (int r = 0; r < 2; ++r) {
        const int t = m0 + 2 * ty + r;
        const float w = wdf[t];
        ((float4*)(out + t * 128))[tx] =
            make_float4(acc1[r][0] + w * (b24.x + acc2[r][0]),
                        acc1[r][1] + w * (b24.y + acc2[r][1]),
                        acc1[r][2] + w * (b24.z + acc2[r][2]),
                        acc1[r][3] + w * (b24.w + acc2[r][3]));
    }
}

// ---------------------------------------------------------------------------
extern "C" void kernel_launch(void* const* d_in, const int* in_sizes, int n_in,
                              void* d_out, int out_size, void* d_ws, size_t ws_size,
                              hipStream_t stream)
{
    const float* x   = (const float*)d_in[0];
    const float* W1  = (const float*)d_in[1];
    const float* b1  = (const float*)d_in[2];
    const float* W2  = (const float*)d_in[3];
    const float* b2  = (const float*)d_in[4];
    const float* Wq  = (const float*)d_in[5];
    const float* bq  = (const float*)d_in[6];
    const float* Wk  = (const float*)d_in[7];
    const float* bk  = (const float*)d_in[8];
    const float* Wv  = (const float*)d_in[9];
    const float* bv  = (const float*)d_in[10];
    const float* Wlr = (const float*)d_in[11];
    const float* blr = (const float*)d_in[12];
    const float* Wm  = (const float*)d_in[13];
    const float* bm  = (const float*)d_in[14];
    const float* Wwd = (const float*)d_in[15];
    const float* bwd = (const float*)d_in[16];

    float* ws = (float*)d_ws;
    float* ko     = ws + 0;         // 512x128  (must precede qo: kBE M=1024)
    float* qo     = ws + 65536;     // 512x128
    float* vo     = ws + 131072;    // 512x128
    float* Z1row  = ws + 196608;    // 512x256
    float* X2row  = ws + 327680;    // 512x256
    float* z1qrow = ws + 458752;    // 512x256
    float* gZ2row = ws + 589824;    // 512x128
    float* gZ1row = ws + 655360;    // 512x256
    float* Xq2row = ws + 786432;    // 512x256
    float* arow1  = ws + 917504;    // 512x256
    float* arow2  = ws + 1048576;   // 512x256
    float* KTr    = ws + 1179648;   // 2 x 128 x 256
    float* X2Tr   = ws + 1245184;   // 2 x 256 x 256
    float* Ssc    = ws + 1376256;   // 512x256
    float* wdf    = ws + 1507328;   // 512
    float* WqT    = ws + 1507840;   // 128x128
    float* WkT    = ws + 1524224;
    float* WvT    = ws + 1540608;
    float* W1T    = ws + 1556992;   // 128x256
    float* W2T    = ws + 1589760;   // 256x128
    float* out    = (float*)d_out;

    k_pre<<<112, 256, 0, stream>>>(Wq, Wk, Wv, W1, W2, WqT, WkT, WvT, W1T, W2T);
    kA<<<98, 256, 0, stream>>>(x, WqT, WkT, WvT, bq, bk, bv,
                               Wlr, blr, Wm, bm, Wwd, bwd,
                               qo, ko, vo, KTr, Ssc, wdf);
    kBE<<<192, 256, 0, stream>>>(ko, qo, W1T, b1, KTr, Ssc,
                                 Z1row, X2row, X2Tr, z1qrow, arow1);
    kC<<<32, 256, 0, stream>>>(X2row, W2T, b2, vo, gZ2row);
    kD<<<64, 256, 0, stream>>>(gZ2row, W2, Z1row, gZ1row);
    kF<<<64, 256, 0, stream>>>(arow1, gZ1row, z1qrow, wdf, Xq2row);
    kG<<<64, 256, 0, stream>>>(Xq2row, X2Tr, Ssc, arow2);
    kH<<<32, 256, 0, stream>>>(arow2, gZ2row, Xq2row, W2T, b2, wdf, out);
}

// Round 12
// 127.111 us; speedup vs baseline: 2.0424x; 1.7559x over previous
//
#include <hip/hip_runtime.h>
#include <hip/hip_bf16.h>

// B=2, L=256, D=128, H=256 fast-weight (TTT-style) forward.
// Exact rewrite: sequential momentum/weight-decay scan -> decay-weighted
// attention with composed decay matrix S = wd_cs @ mom_cs via the stable
// O(L^2) recurrence (all exponents <= 0 in the live region).
//
// v12 = v9 (best known: 133.6us) + fast scan. Diagnosis: the serial S-matrix
// recurrence (256 iters x ~375cyc of ds_read->exp->fma->store chain on 2
// blocks) has been a hidden ~40-45us floor since R6 (R11's kA=47us with a
// ~4us GEMM share exposed it). Fix: batch-8 iterations -- float4 LDS reads +
// 8 up-front __expf, then an 8-fma dependent chain; wave-causal start
// (ll0 = m & ~63) with explicit zero-fill of the consumed 3-wide
// above-diagonal band. Operation order identical -> bitwise-same output.

#define Bc 2
#define Lc 256
#define Dc 128
#define Hc 256

__device__ __forceinline__ float sigf(float z)  { return 1.f / (1.f + expf(-z)); }
__device__ __forceinline__ float siluf(float z) { return z * sigf(z); }
// replicates reference silu_backward exactly: s + sigmoid(z)*(1-s), s=silu(z)
__device__ __forceinline__ float silubwdf(float z) {
    float sg = sigf(z);
    float s  = z * sg;
    return s + sg * (1.f - s);
}
__device__ __forceinline__ float softplusf(float z) {
    if (z > 20.f)  return z;
    if (z < -20.f) return expf(z);
    return log1pf(expf(z));
}
__device__ __forceinline__ float dot4(float4 a, float4 b) {
    return a.x*b.x + a.y*b.y + a.z*b.z + a.w*b.w;
}

// ---------------------------------------------------------------------------
// K0: pure weight interleave, 144 blocks x 256 threads.
// ---------------------------------------------------------------------------
__global__ __launch_bounds__(256) void k_pre(
    const float* __restrict__ Wq, const float* __restrict__ Wk,
    const float* __restrict__ Wv, const float* __restrict__ W1,
    const float* __restrict__ W2,
    float4* __restrict__ Wq4, float4* __restrict__ Wk4, float4* __restrict__ Wv4,
    float4* __restrict__ W14, float4* __restrict__ W2q4, float4* __restrict__ W2c4)
{
    const int bb = blockIdx.x;
    if (bb < 112) {
        const float* in; float4* o; int M, N, base;
        if      (bb < 16) { in = Wq; o = Wq4;  M = 128; N = 128; base = 0;  }
        else if (bb < 32) { in = Wk; o = Wk4;  M = 128; N = 128; base = 16; }
        else if (bb < 48) { in = Wv; o = Wv4;  M = 128; N = 128; base = 32; }
        else if (bb < 80) { in = W1; o = W14;  M = 256; N = 128; base = 48; }
        else              { in = W2; o = W2q4; M = 128; N = 256; base = 80; }
        const int idx = (bb - base) * 256 + threadIdx.x;
        const int r = idx % M, g = idx / M;
        o[idx] = *(const float4*)(in + r * N + 4 * g);
    } else {
        const int idx = (bb - 112) * 256 + threadIdx.x;   // 0..8191
        const int c = idx & 255, g = idx >> 8;
        W2c4[idx] = make_float4(W2[(4*g+0)*Hc + c], W2[(4*g+1)*Hc + c],
                                W2[(4*g+2)*Hc + c], W2[(4*g+3)*Hc + c]);
    }
}

// ---------------------------------------------------------------------------
// K1: token fwd + grads (blocks 0..255, 2 tokens/block) +
//     gate/decay scan (blocks 256/257, one per batch).
// ---------------------------------------------------------------------------
__global__ __launch_bounds__(512, 4) void k_token(
    const float* __restrict__ x,
    const float* __restrict__ b1v, const float* __restrict__ b2v,
    const float* __restrict__ bq,  const float* __restrict__ bk,
    const float* __restrict__ bv,
    const float4* __restrict__ Wq4, const float4* __restrict__ Wk4,
    const float4* __restrict__ Wv4, const float4* __restrict__ W14,
    const float4* __restrict__ W2q4, const float4* __restrict__ W2c4,
    const float* __restrict__ Wlr, const float* __restrict__ blr,
    const float* __restrict__ Wm,  const float* __restrict__ bm,
    const float* __restrict__ Wwd, const float* __restrict__ bwd,
    float* __restrict__ qo, float* __restrict__ KT, float* __restrict__ X2T,
    float* __restrict__ z1q, float* __restrict__ GZ1, float* __restrict__ GZ2,
    float* __restrict__ Ssc, float* __restrict__ wdf)
{
    const int bb  = blockIdx.x;
    const int tid = threadIdx.x;

    if (bb >= Bc * Lc / 2) {
        // ================= gate/decay scan (1 block per batch) =============
        __shared__ __align__(16) float lrS[Lc];
        __shared__ __align__(16) float lwS[Lc];
        __shared__ __align__(16) float ewdS[Lc];
        __shared__ __align__(16) float clmS[Lc];
        __shared__ __align__(16) float cwdS[Lc];
        const int b = bb - Bc * Lc / 2;
        const int l = tid;
        if (l < Lc) {
            const float4* xr4 = (const float4*)(x + (b * Lc + l) * Dc);
            const float4* wl4 = (const float4*)Wlr;
            const float4* wm4 = (const float4*)Wm;
            const float4* ww4 = (const float4*)Wwd;
            float dlr = blr[0], dm = bm[0], dw = bwd[0];
            #pragma unroll 4
            for (int j = 0; j < Dc / 4; ++j) {
                float4 xv = xr4[j];
                dlr += dot4(wl4[j], xv);
                dm  += dot4(wm4[j], xv);
                dw  += dot4(ww4[j], xv);
            }
            lrS[l] = softplusf(dlr);
            float lm = -softplusf(-dm);   // log sigmoid
            float lw = -softplusf(-dw);
            lwS[l]  = lw;
            clmS[l] = lm;
            cwdS[l] = lw;
        }
        __syncthreads();
        for (int off = 1; off < Lc; off <<= 1) {
            float a = 0.f, c = 0.f;
            if (l < Lc && l >= off) { a = clmS[l - off]; c = cwdS[l - off]; }
            __syncthreads();
            if (l < Lc) { clmS[l] += a; cwdS[l] += c; }
            __syncthreads();
        }
        if (l < Lc) {
            wdf[b * Lc + l] = expf(cwdS[l]);
            ewdS[l] = __expf(lwS[l]);
        }
        __syncthreads();
        if (l < Lc) {
            // S[l,m] recurrence, thread = m; batch-8 pipelined.
            const int   m     = l;
            const float clm_m = clmS[m];
            const float lrm   = lrS[m];
            float* outp = Ssc + (b * Lc) * Lc + m;
            // wave-uniform causal start (each wave starts at its min m)
            const int ll0 = m & ~63;
            // zero-fill the consumed above-diagonal band (<=3) below ll0
            {
                int zs = m - 3 < 0 ? 0 : m - 3;
                for (int ll = zs; ll < ll0; ++ll) outp[ll * Lc] = 0.f;
            }
            float s = 0.f;
            for (int ll4 = ll0; ll4 < Lc; ll4 += 8) {
                float4 cla = *(const float4*)&clmS[ll4];
                float4 clb = *(const float4*)&clmS[ll4 + 4];
                float4 ewa = *(const float4*)&ewdS[ll4];
                float4 ewb = *(const float4*)&ewdS[ll4 + 4];
                float ew[8] = {ewa.x, ewa.y, ewa.z, ewa.w,
                               ewb.x, ewb.y, ewb.z, ewb.w};
                float e2[8];
                e2[0] = __expf(cla.x - clm_m); e2[1] = __expf(cla.y - clm_m);
                e2[2] = __expf(cla.z - clm_m); e2[3] = __expf(cla.w - clm_m);
                e2[4] = __expf(clb.x - clm_m); e2[5] = __expf(clb.y - clm_m);
                e2[6] = __expf(clb.z - clm_m); e2[7] = __expf(clb.w - clm_m);
                #pragma unroll
                for (int u = 0; u < 8; ++u) {
                    const int ll = ll4 + u;
                    s = (ll >= m) ? (ew[u] * s + e2[u]) : 0.f;
                    outp[ll * Lc] = s * lrm;
                }
            }
        }
        return;
    }

    // ================= token work: 2 tokens/block ==========================
    __shared__ __align__(16) float xs[2][Dc], qs[2][Dc], ks[2][Dc];
    __shared__ __align__(16) float X2s[2][Hc], z1s[2][Hc], gZ2s[2][Dc];
    __shared__ __align__(16) float pv[2][2][Dc], pz[4][2][Dc], pg[2][2][Hc];

    const int t0 = bb * 2;
    const int b  = t0 >> 8;
    const int l0 = t0 & 255;

    if (tid < 2 * Dc / 4)
        ((float4*)&xs[0][0])[tid] = ((const float4*)(x + t0 * Dc))[tid];
    __syncthreads();

    // --- phase 1: g0=q, g1=k, g2/g3=v halves; each load feeds both tokens ---
    {
        const int g = tid >> 7, c = tid & 127;
        float4 wb[16];
        if (g < 2) {
            const float4* W = g ? Wk4 : Wq4;
            float a0 = (g ? bk : bq)[c], a1 = a0;
            for (int j4 = 0; j4 < 32; j4 += 16) {
                #pragma unroll
                for (int u = 0; u < 16; ++u) wb[u] = W[(j4+u) * Dc + c];
                #pragma unroll
                for (int u = 0; u < 16; ++u) {
                    a0 += dot4(wb[u], *(const float4*)&xs[0][4*(j4+u)]);
                    a1 += dot4(wb[u], *(const float4*)&xs[1][4*(j4+u)]);
                }
            }
            if (g == 0) {
                qs[0][c] = a0; qs[1][c] = a1;
                qo[t0 * Dc + c] = a0;
                qo[(t0 + 1) * Dc + c] = a1;
            } else {
                ks[0][c] = a0; ks[1][c] = a1;
                float* ktp = KT + (size_t)b * 32768;
                ktp[((c >> 2) * Lc + l0 + 0) * 4 + (c & 3)] = a0;
                ktp[((c >> 2) * Lc + l0 + 1) * 4 + (c & 3)] = a1;
            }
        } else {
            const int half = g - 2, j0 = half * 16;
            float av0 = 0.f, av1 = 0.f;
            #pragma unroll
            for (int u = 0; u < 16; ++u) wb[u] = Wv4[(j0+u) * Dc + c];
            #pragma unroll
            for (int u = 0; u < 16; ++u) {
                av0 += dot4(wb[u], *(const float4*)&xs[0][4*(j0+u)]);
                av1 += dot4(wb[u], *(const float4*)&xs[1][4*(j0+u)]);
            }
            pv[half][0][c] = av0; pv[half][1][c] = av1;
        }
    }
    __syncthreads();

    // --- phase 2: which=0 -> Z1 (from k), which=1 -> z1q (from q) ---
    {
        const int which = tid >> 8, h = tid & 255;
        const float (*src)[Dc] = which ? qs : ks;
        float a0 = b1v[h], a1 = a0;
        float4 wb[16];
        for (int d4 = 0; d4 < 32; d4 += 16) {
            #pragma unroll
            for (int u = 0; u < 16; ++u) wb[u] = W14[(d4+u) * Hc + h];
            #pragma unroll
            for (int u = 0; u < 16; ++u) {
                a0 += dot4(wb[u], *(const float4*)&src[0][4*(d4+u)]);
                a1 += dot4(wb[u], *(const float4*)&src[1][4*(d4+u)]);
            }
        }
        if (which == 0) {
            z1s[0][h] = a0; z1s[1][h] = a1;
            float s0 = siluf(a0), s1 = siluf(a1);
            X2s[0][h] = s0; X2s[1][h] = s1;
            float* xtp = X2T + (size_t)b * 65536;
            xtp[((h >> 2) * Lc + l0 + 0) * 4 + (h & 3)] = s0;
            xtp[((h >> 2) * Lc + l0 + 1) * 4 + (h & 3)] = s1;
        } else {
            z1q[(t0 + 0) * Hc + h] = a0;
            z1q[(t0 + 1) * Hc + h] = a1;
        }
    }
    __syncthreads();

    // --- phase 3: Z2 4-way h-split, both tokens per load ---
    {
        const int q4g = tid >> 7, d = tid & 127;
        const int h0 = q4g * 16;
        float a0 = 0.f, a1 = 0.f;
        float4 wb[16];
        #pragma unroll
        for (int u = 0; u < 16; ++u) wb[u] = W2q4[(h0+u) * Dc + d];
        #pragma unroll
        for (int u = 0; u < 16; ++u) {
            a0 += dot4(wb[u], *(const float4*)&X2s[0][4*(h0+u)]);
            a1 += dot4(wb[u], *(const float4*)&X2s[1][4*(h0+u)]);
        }
        pz[q4g][0][d] = a0; pz[q4g][1][d] = a1;
    }
    __syncthreads();
    if (tid < 2 * Dc) {
        const int t = tid >> 7, d = tid & 127;
        float g = pz[0][t][d] + pz[1][t][d] + pz[2][t][d] + pz[3][t][d] + b2v[d]
                - (pv[0][t][d] + pv[1][t][d] + bv[d]);
        gZ2s[t][d] = g;
        const int l = l0 + t;
        GZ2[(size_t)b * 32768 + ((l >> 2) * Dc + d) * 4 + (l & 3)] = g;
    }
    __syncthreads();

    // --- phase 4: gX2 2-way d-split; gZ1 = gX2 * silu_bwd(Z1) ---
    {
        const int which = tid >> 8, h = tid & 255;
        const int d0 = which * 16;
        float a0 = 0.f, a1 = 0.f;
        float4 wb[16];
        #pragma unroll
        for (int u = 0; u < 16; ++u) wb[u] = W2c4[(d0+u) * Hc + h];
        #pragma unroll
        for (int u = 0; u < 16; ++u) {
            a0 += dot4(wb[u], *(const float4*)&gZ2s[0][4*(d0+u)]);
            a1 += dot4(wb[u], *(const float4*)&gZ2s[1][4*(d0+u)]);
        }
        pg[which][0][h] = a0; pg[which][1][h] = a1;
    }
    __syncthreads();
    {
        const int t = tid >> 8, h = tid & 255;
        const int l = l0 + t;
        GZ1[(size_t)b * 65536 + ((l >> 2) * Hc + h) * 4 + (l & 3)]
            = (pg[0][t][h] + pg[1][t][h]) * silubwdf(z1s[t][h]);
    }
}

// ---------------------------------------------------------------------------
// K2: fused query. 256 blocks x 512 threads, 2 tokens/block; causal-bounded.
// ---------------------------------------------------------------------------
__global__ __launch_bounds__(512, 4) void k_query(
    const float* __restrict__ qo,  const float* __restrict__ KT,
    const float* __restrict__ X2T, const float* __restrict__ GZ1,
    const float* __restrict__ GZ2, const float* __restrict__ z1q,
    const float* __restrict__ Ssc, const float* __restrict__ wdf,
    const float4* __restrict__ W2q4, const float* __restrict__ b2v,
    float* __restrict__ out)
{
    __shared__ __align__(16) float qs[2][Dc], ss[2][Lc], arow[2][Lc], xq2s[2][Hc];
    __shared__ __align__(16) float ps[2][2][Lc], pq[2][2][Hc];
    __shared__ __align__(16) float pm[4][2][Dc], pw[4][2][Dc];

    const int t0  = blockIdx.x * 2;
    const int b   = t0 >> 8;
    const int l0  = t0 & 255;
    const int tid = threadIdx.x;
    const int M4  = ((l0 + 1) >> 2) + 1;   // causal bound for the PAIR (exact:
    const int mPad = M4 * 4;               // ss is zero above each row's diag)

    if (tid < 2 * Dc / 4)
        ((float4*)&qs[0][0])[tid] = ((const float4*)(qo + t0 * Dc))[tid];
    if (tid < Lc) {
        ss[0][tid] = Ssc[(t0 + 0) * Lc + tid];
        ss[1][tid] = Ssc[(t0 + 1) * Lc + tid];
    }
    const float wdf0 = wdf[t0 + 0], wdf1 = wdf[t0 + 1];
    __syncthreads();

    // --- score1 partials: 2-way d-split, both tokens per load ---
    {
        const int which = tid >> 8, m = tid & 255;
        if (m < mPad) {
            const float4* ktb = (const float4*)(KT + (size_t)b * 32768);
            const int d0 = which * 16;
            float acc0 = 0.f, acc1 = 0.f;
            float4 wb[16];
            #pragma unroll
            for (int u = 0; u < 16; ++u) wb[u] = ktb[(d0+u) * Lc + m];
            #pragma unroll
            for (int u = 0; u < 16; ++u) {
                acc0 += dot4(wb[u], *(const float4*)&qs[0][4*(d0+u)]);
                acc1 += dot4(wb[u], *(const float4*)&qs[1][4*(d0+u)]);
            }
            ps[which][0][m] = acc0; ps[which][1][m] = acc1;
        }
    }
    __syncthreads();
    {
        const int t = tid >> 8, m = tid & 255;
        if (m < mPad)
            arow[t][m] = ss[t][m] * (ps[0][t][m] + ps[1][t][m] + 1.f);
    }
    __syncthreads();

    // --- Zq1 partials: 2-way strided m4-split, both tokens per load ---
    {
        const int which = tid >> 8, h = tid & 255;
        const float4* g = (const float4*)(GZ1 + (size_t)b * 65536);
        const float4* ar0 = (const float4*)&arow[0][0];
        const float4* ar1 = (const float4*)&arow[1][0];
        float acc0 = 0.f, acc1 = 0.f;
        float4 wb[16];
        int m4 = which;
        for (; m4 + 30 < M4; m4 += 32) {
            #pragma unroll
            for (int u = 0; u < 16; ++u) wb[u] = g[(m4 + 2*u) * Hc + h];
            #pragma unroll
            for (int u = 0; u < 16; ++u) {
                acc0 += dot4(wb[u], ar0[m4 + 2*u]);
                acc1 += dot4(wb[u], ar1[m4 + 2*u]);
            }
        }
        for (; m4 < M4; m4 += 2) {
            float4 gv = g[m4 * Hc + h];
            acc0 += dot4(gv, ar0[m4]);
            acc1 += dot4(gv, ar1[m4]);
        }
        pq[which][0][h] = acc0; pq[which][1][h] = acc1;
    }
    __syncthreads();
    {
        const int t = tid >> 8, h = tid & 255;
        const float w = t ? wdf1 : wdf0;
        xq2s[t][h] = siluf(pq[0][t][h] + pq[1][t][h]
                           + w * z1q[(t0 + t) * Hc + h]);
    }
    __syncthreads();

    // --- score2 partials: 2-way h-split, both tokens per load ---
    {
        const int which = tid >> 8, m = tid & 255;
        if (m < mPad) {
            const float4* xtb = (const float4*)(X2T + (size_t)b * 65536);
            const int h0 = which * 32;
            float acc0 = 0.f, acc1 = 0.f;
            float4 wb[16];
            for (int h4 = h0; h4 < h0 + 32; h4 += 16) {
                #pragma unroll
                for (int u = 0; u < 16; ++u) wb[u] = xtb[(h4+u) * Lc + m];
                #pragma unroll
                for (int u = 0; u < 16; ++u) {
                    acc0 += dot4(wb[u], *(const float4*)&xq2s[0][4*(h4+u)]);
                    acc1 += dot4(wb[u], *(const float4*)&xq2s[1][4*(h4+u)]);
                }
            }
            ps[which][0][m] = acc0; ps[which][1][m] = acc1;
        }
    }
    __syncthreads();
    {
        const int t = tid >> 8, m = tid & 255;
        if (m < mPad)
            arow[t][m] = ss[t][m] * (ps[0][t][m] + ps[1][t][m] + 1.f);
    }
    __syncthreads();

    // --- Zq2: 4-way split (m-part strided m4, w-part chunked h) ---
    {
        const int q4g = tid >> 7, d = tid & 127;
        const float4* g2  = (const float4*)(GZ2 + (size_t)b * 32768);
        const float4* ar0 = (const float4*)&arow[0][0];
        const float4* ar1 = (const float4*)&arow[1][0];
        float am0 = 0.f, am1 = 0.f, aw0 = 0.f, aw1 = 0.f;
        float4 wb[16];
        int m4 = q4g;
        for (; m4 + 60 < M4; m4 += 64) {
            #pragma unroll
            for (int u = 0; u < 16; ++u) wb[u] = g2[(m4 + 4*u) * Dc + d];
            #pragma unroll
            for (int u = 0; u < 16; ++u) {
                am0 += dot4(wb[u], ar0[m4 + 4*u]);
                am1 += dot4(wb[u], ar1[m4 + 4*u]);
            }
        }
        for (; m4 < M4; m4 += 4) {
            float4 gv = g2[m4 * Dc + d];
            am0 += dot4(gv, ar0[m4]);
            am1 += dot4(gv, ar1[m4]);
        }
        const int h0 = q4g * 16;
        #pragma unroll
        for (int u = 0; u < 16; ++u) wb[u] = W2q4[(h0+u) * Dc + d];
        #pragma unroll
        for (int u = 0; u < 16; ++u) {
            aw0 += dot4(wb[u], *(const float4*)&xq2s[0][4*(h0+u)]);
            aw1 += dot4(wb[u], *(const float4*)&xq2s[1][4*(h0+u)]);
        }
        pm[q4g][0][d] = am0; pm[q4g][1][d] = am1;
        pw[q4g][0][d] = aw0; pw[q4g][1][d] = aw1;
    }
    __syncthreads();
    if (tid < 2 * Dc) {
        const int t = tid >> 7, d = tid & 127;
        const float w = t ? wdf1 : wdf0;
        out[(t0 + t) * Dc + d] =
            (pm[0][t][d] + pm[1][t][d] + pm[2][t][d] + pm[3][t][d])
            + w * (b2v[d] + pw[0][t][d] + pw[1][t][d] + pw[2][t][d] + pw[3][t][d]);
    }
}

// ---------------------------------------------------------------------------
extern "C" void kernel_launch(void* const* d_in, const int* in_sizes, int n_in,
                              void* d_out, int out_size, void* d_ws, size_t ws_size,
                              hipStream_t stream)
{
    const float* x   = (const float*)d_in[0];
    const float* W1  = (const float*)d_in[1];
    const float* b1  = (const float*)d_in[2];
    const float* W2  = (const float*)d_in[3];
    const float* b2  = (const float*)d_in[4];
    const float* Wq  = (const float*)d_in[5];
    const float* bq  = (const float*)d_in[6];
    const float* Wk  = (const float*)d_in[7];
    const float* bk  = (const float*)d_in[8];
    const float* Wv  = (const float*)d_in[9];
    const float* bv  = (const float*)d_in[10];
    const float* Wlr = (const float*)d_in[11];
    const float* blr = (const float*)d_in[12];
    const float* Wm  = (const float*)d_in[13];
    const float* bm  = (const float*)d_in[14];
    const float* Wwd = (const float*)d_in[15];
    const float* bwd = (const float*)d_in[16];

    float* ws = (float*)d_ws;
    float*  qo   = ws;                       // 65536
    float*  KT   = ws + 65536;               // 65536
    float*  X2T  = ws + 131072;              // 131072
    float*  GZ1  = ws + 262144;              // 131072
    float*  GZ2  = ws + 393216;              // 65536
    float*  z1q  = ws + 458752;              // 131072
    float*  Ssc  = ws + 589824;              // 131072
    float*  wdf  = ws + 720896;              // 512
    float4* Wq4  = (float4*)(ws + 721408);   // 16384 floats
    float4* Wk4  = (float4*)(ws + 737792);
    float4* Wv4  = (float4*)(ws + 754176);
    float4* W14  = (float4*)(ws + 770560);   // 32768
    float4* W2q4 = (float4*)(ws + 803328);   // 32768
    float4* W2c4 = (float4*)(ws + 836096);   // 32768
    float*  out  = (float*)d_out;

    k_pre<<<144, 256, 0, stream>>>(Wq, Wk, Wv, W1, W2,
                                   Wq4, Wk4, Wv4, W14, W2q4, W2c4);
    k_token<<<Bc * Lc / 2 + Bc, 512, 0, stream>>>(x, b1, b2, bq, bk, bv,
                                                  Wq4, Wk4, Wv4, W14, W2q4, W2c4,
                                                  Wlr, blr, Wm, bm, Wwd, bwd,
                                                  qo, KT, X2T, z1q, GZ1, GZ2,
                                                  Ssc, wdf);
    k_query<<<Bc * Lc / 2, 512, 0, stream>>>(qo, KT, X2T, GZ1, GZ2, z1q,
                                             Ssc, wdf, W2q4, b2, out);
}